// Round 1
// baseline (40.962 us; speedup 1.0000x reference)
//
#include <hip/hip_runtime.h>
#include <hip/hip_bf16.h>

#define SEQL 4096
#define DIM  1024
#define SEGLEN 32
#define NSEG 128   // SEGLEN*NSEG == SEQL (worst case: all tokens are boundaries)

// ---------------------------------------------------------------------------
// Kernel 1: per-batch compaction. Block of 1024 threads, 4 tokens/thread.
// Produces: bpos[k] (position of k-th boundary), coefA[k]=1-p, coefB[k]=p, nb.
// Mask is read as int; nonzero-bits test works for int32 0/1 and float 0/1.
// ---------------------------------------------------------------------------
__global__ __launch_bounds__(1024) void prep_kernel(
    const float* __restrict__ prob, const int* __restrict__ mask,
    int* __restrict__ bpos, int* __restrict__ nb,
    float* __restrict__ coefA, float* __restrict__ coefB) {
  const int b = blockIdx.x;
  const int tid = threadIdx.x;
  const int* mb = mask + b * SEQL;
  const float* pb = prob + b * SEQL;

  int4 m = reinterpret_cast<const int4*>(mb)[tid];
  int mv[4] = { m.x != 0, m.y != 0, m.z != 0, m.w != 0 };
  int c0 = mv[0] + mv[1] + mv[2] + mv[3];

  __shared__ int sc[1024];
  sc[tid] = c0;
  __syncthreads();
  // Hillis-Steele inclusive scan over per-thread counts
  for (int off = 1; off < 1024; off <<= 1) {
    int add = (tid >= off) ? sc[tid - off] : 0;
    __syncthreads();
    sc[tid] += add;
    __syncthreads();
  }
  int incl = sc[tid];
  int excl = incl - c0;
  if (tid == 1023) nb[b] = incl;

  int run = excl;
#pragma unroll
  for (int j = 0; j < 4; ++j) {
    if (mv[j]) {
      int t = tid * 4 + j;
      float pv = pb[t];
      pv = fminf(fmaxf(pv, 1e-4f), 1.0f - 1e-4f);
      bpos[b * SEQL + run] = t;
      coefA[b * SEQL + run] = 1.0f - pv;
      coefB[b * SEQL + run] = pv;
      run++;
    }
  }
}

// ---------------------------------------------------------------------------
// Kernel 2: per-segment local EMA (carry-in 0) -> Bseg[b][s][d]
// grid = (DIM/256, NSEG, batch), block = 256
// ---------------------------------------------------------------------------
__global__ __launch_bounds__(256) void scan_local_kernel(
    const float* __restrict__ h, const int* __restrict__ bpos,
    const float* __restrict__ coefA, const float* __restrict__ coefB,
    const int* __restrict__ nb, float* __restrict__ Bseg) {
  const int b = blockIdx.z;
  const int s = blockIdx.y;
  const int d = blockIdx.x * 256 + threadIdx.x;
  const int n = nb[b];
  const int k0 = s * SEGLEN;
  if (k0 >= n) return;
  const int k1 = min(k0 + SEGLEN, n);

  const float* hb = h + (size_t)b * SEQL * DIM;
  const int* bp = bpos + b * SEQL;
  const float* ca = coefA + b * SEQL;
  const float* cb = coefB + b * SEQL;

  float H = 0.0f;
#pragma unroll 8
  for (int k = k0; k < k1; ++k) {
    float x = hb[(size_t)bp[k] * DIM + d];
    H = fmaf(ca[k], H, cb[k] * x);
  }
  Bseg[((size_t)b * NSEG + s) * DIM + d] = H;
}

// ---------------------------------------------------------------------------
// Kernel 3: combine carries across segments. 1 block per batch, 1024 threads
// (one per channel). Aseg (channel-independent segment decay products) in LDS.
// carry[b][s][d] = state BEFORE segment s.
// ---------------------------------------------------------------------------
__global__ __launch_bounds__(1024) void combine_kernel(
    const float* __restrict__ coefA, const int* __restrict__ nb,
    const float* __restrict__ Bseg, float* __restrict__ carry) {
  const int b = blockIdx.x;
  const int d = threadIdx.x;
  const int n = nb[b];
  const int S = (n + SEGLEN - 1) / SEGLEN;

  __shared__ float Aseg[NSEG];
  if (d < NSEG) {
    int k0 = d * SEGLEN;
    int k1 = min(k0 + SEGLEN, n);
    float a = 1.0f;
    for (int k = k0; k < k1; ++k) a *= coefA[b * SEQL + k];
    Aseg[d] = a;
  }
  __syncthreads();

  float C = 0.0f;
  for (int s = 0; s < S; ++s) {
    size_t o = ((size_t)b * NSEG + s) * DIM + d;
    carry[o] = C;
    C = fmaf(Aseg[s], C, Bseg[o]);
  }
}

// ---------------------------------------------------------------------------
// Kernel 4: re-run each segment from its carry-in; fused run-length expansion
// writes H_k to every output row in [bpos[k], bpos[k+1]).  Covers all rows.
// grid = (DIM/256, NSEG, batch), block = 256
// ---------------------------------------------------------------------------
__global__ __launch_bounds__(256) void scan_final_kernel(
    const float* __restrict__ h, const int* __restrict__ bpos,
    const float* __restrict__ coefA, const float* __restrict__ coefB,
    const int* __restrict__ nb, const float* __restrict__ carry,
    float* __restrict__ out) {
  const int b = blockIdx.z;
  const int s = blockIdx.y;
  const int d = blockIdx.x * 256 + threadIdx.x;
  const int n = nb[b];
  const int k0 = s * SEGLEN;
  if (k0 >= n) return;
  const int k1 = min(k0 + SEGLEN, n);

  const float* hb = h + (size_t)b * SEQL * DIM;
  float* ob = out + (size_t)b * SEQL * DIM;
  const int* bp = bpos + b * SEQL;
  const float* ca = coefA + b * SEQL;
  const float* cb = coefB + b * SEQL;

  float H = carry[((size_t)b * NSEG + s) * DIM + d];
  for (int k = k0; k < k1; ++k) {
    int t = bp[k];
    float x = hb[(size_t)t * DIM + d];
    H = fmaf(ca[k], H, cb[k] * x);
    int tnext = (k + 1 < n) ? bp[k + 1] : SEQL;
    for (int tt = t; tt < tnext; ++tt) {
      ob[(size_t)tt * DIM + d] = H;
    }
  }
}

// ---------------------------------------------------------------------------
extern "C" void kernel_launch(void* const* d_in, const int* in_sizes, int n_in,
                              void* d_out, int out_size, void* d_ws, size_t ws_size,
                              hipStream_t stream) {
  const float* h    = (const float*)d_in[0];   // (2, 4096, 1024) f32
  const float* p    = (const float*)d_in[1];   // (2, 4096) f32
  const int*   mask = (const int*)d_in[2];     // (2, 4096) bool->int
  float* out = (float*)d_out;                  // (2, 4096, 1024) f32

  // workspace layout
  int* bpos = (int*)d_ws;                      // 2*4096 ints
  int* nb   = bpos + 2 * SEQL;                 // 2 ints (padded to 16)
  float* coefA = (float*)(nb + 16);            // 2*4096 f32
  float* coefB = coefA + 2 * SEQL;             // 2*4096 f32
  float* Bseg  = coefB + 2 * SEQL;             // 2*NSEG*DIM f32 (1 MB)
  float* carry = Bseg + 2 * NSEG * DIM;        // 2*NSEG*DIM f32 (1 MB)

  prep_kernel<<<dim3(2), 1024, 0, stream>>>(p, mask, bpos, nb, coefA, coefB);

  dim3 sg(DIM / 256, NSEG, 2);
  scan_local_kernel<<<sg, 256, 0, stream>>>(h, bpos, coefA, coefB, nb, Bseg);

  combine_kernel<<<dim3(2), 1024, 0, stream>>>(coefA, nb, Bseg, carry);

  scan_final_kernel<<<sg, 256, 0, stream>>>(h, bpos, coefA, coefB, nb, carry, out);
}

// Round 2
// 28.304 us; speedup vs baseline: 1.4472x; 1.4472x over previous
//
#include <hip/hip_runtime.h>
#include <hip/hip_bf16.h>

#define SEQL 4096
#define DIM  1024
#define SEGLEN 16
#define NSEG (SEQL / SEGLEN)   // 256: worst case every token is a boundary

// ---------------------------------------------------------------------------
// Kernel 1: per-batch compaction + segment decay products.
// 1 block of 1024 threads per batch, 4 tokens/thread.
// Wave-level shuffle scan (2 barriers) instead of Hillis-Steele (20 barriers).
// Outputs: bpos[k], coefA[k]=1-p, coefB[k]=p (compacted), nb, Aseg[s].
// ---------------------------------------------------------------------------
__global__ __launch_bounds__(1024) void prep_kernel(
    const float* __restrict__ prob, const int* __restrict__ mask,
    int* __restrict__ bpos, int* __restrict__ nb,
    float* __restrict__ coefA, float* __restrict__ coefB,
    float* __restrict__ Aseg) {
  const int b = blockIdx.x;
  const int tid = threadIdx.x;
  const int wid = tid >> 6;
  const int lane = tid & 63;
  const int* mb = mask + b * SEQL;
  const float* pb = prob + b * SEQL;

  int4 m = reinterpret_cast<const int4*>(mb)[tid];
  int mv[4] = { m.x != 0, m.y != 0, m.z != 0, m.w != 0 };
  int c0 = mv[0] + mv[1] + mv[2] + mv[3];

  // wave-64 inclusive scan of c0
  int v = c0;
#pragma unroll
  for (int off = 1; off < 64; off <<= 1) {
    int t = __shfl_up(v, off, 64);
    if (lane >= off) v += t;
  }

  __shared__ int wsum[16];
  if (lane == 63) wsum[wid] = v;
  __syncthreads();
  if (tid < 16) {
    int x = wsum[tid];
#pragma unroll
    for (int off = 1; off < 16; off <<= 1) {
      int t = __shfl_up(x, off, 64);
      if (tid >= off) x += t;
    }
    wsum[tid] = x;   // inclusive wave sums
  }
  __syncthreads();
  int wexcl = (wid > 0) ? wsum[wid - 1] : 0;
  int incl = wexcl + v;
  int excl = incl - c0;
  int n = wsum[15];
  if (tid == 0) nb[b] = n;

  // compact into LDS
  __shared__ int   bp_l[SEQL];
  __shared__ float a_l[SEQL];
  __shared__ float b_l[SEQL];
  int run = excl;
#pragma unroll
  for (int j = 0; j < 4; ++j) {
    if (mv[j]) {
      int t = tid * 4 + j;
      float pv = pb[t];
      pv = fminf(fmaxf(pv, 1e-4f), 1.0f - 1e-4f);
      bp_l[run] = t;
      a_l[run] = 1.0f - pv;
      b_l[run] = pv;
      run++;
    }
  }
  __syncthreads();

  // coalesced write-out of compacted arrays
  for (int i = tid; i < n; i += 1024) {
    bpos[b * SEQL + i] = bp_l[i];
    coefA[b * SEQL + i] = a_l[i];
    coefB[b * SEQL + i] = b_l[i];
  }

  // per-segment decay products (channel-independent scalars)
  int S = (n + SEGLEN - 1) / SEGLEN;
  if (tid < S) {
    int k0 = tid * SEGLEN;
    int k1 = min(k0 + SEGLEN, n);
    float a = 1.0f;
    for (int k = k0; k < k1; ++k) a *= a_l[k];
    Aseg[b * NSEG + tid] = a;
  }
}

// ---------------------------------------------------------------------------
// Kernel 2: per-segment local EMA from 0; stores EVERY local boundary state.
// grid = (DIM/256, NSEG, batch), block = 256. ~512 active blocks.
// ---------------------------------------------------------------------------
__global__ __launch_bounds__(256) void scan_local_kernel(
    const float* __restrict__ h, const int* __restrict__ bpos,
    const float* __restrict__ coefA, const float* __restrict__ coefB,
    const int* __restrict__ nb, float* __restrict__ states) {
  const int b = blockIdx.z;
  const int s = blockIdx.y;
  const int d = blockIdx.x * 256 + threadIdx.x;
  const int n = nb[b];
  const int k0 = s * SEGLEN;
  if (k0 >= n) return;
  const int k1 = min(k0 + SEGLEN, n);

  const float* hb = h + (size_t)b * SEQL * DIM;
  float* st = states + (size_t)b * SEQL * DIM;
  const int* bp = bpos + b * SEQL;
  const float* ca = coefA + b * SEQL;
  const float* cb = coefB + b * SEQL;

  float H = 0.0f;
  if (k1 - k0 == SEGLEN) {
#pragma unroll
    for (int kk = 0; kk < SEGLEN; ++kk) {
      int k = k0 + kk;
      float x = hb[(size_t)bp[k] * DIM + d];
      H = fmaf(ca[k], H, cb[k] * x);
      st[(size_t)k * DIM + d] = H;
    }
  } else {
    for (int k = k0; k < k1; ++k) {
      float x = hb[(size_t)bp[k] * DIM + d];
      H = fmaf(ca[k], H, cb[k] * x);
      st[(size_t)k * DIM + d] = H;
    }
  }
}

// ---------------------------------------------------------------------------
// Kernel 3: carry via short backward weighted sum (scalar weight underflows
// after ~5 segments -> uniform early break), then independent per-boundary
// state finalize + fused run-length expansion writes. No serial chains.
// grid = (DIM/256, NSEG, batch), block = 256.
// ---------------------------------------------------------------------------
__global__ __launch_bounds__(256) void final_kernel(
    const int* __restrict__ bpos, const float* __restrict__ coefA,
    const int* __restrict__ nb, const float* __restrict__ Aseg,
    const float* __restrict__ states, float* __restrict__ out) {
  const int b = blockIdx.z;
  const int s = blockIdx.y;
  const int d = blockIdx.x * 256 + threadIdx.x;
  const int n = nb[b];
  const int k0 = s * SEGLEN;
  if (k0 >= n) return;
  const int k1 = min(k0 + SEGLEN, n);

  const float* st = states + (size_t)b * SEQL * DIM;
  float* ob = out + (size_t)b * SEQL * DIM;
  const int* bp = bpos + b * SEQL;
  const float* ca = coefA + b * SEQL;
  const float* As = Aseg + b * NSEG;

  // carry into this segment: C = sum_{j<s} (prod_{j<i<s} Aseg_i) * lastState_j
  float C = 0.0f;
  float w = 1.0f;
  for (int j = s - 1; j >= 0; --j) {
    C = fmaf(w, st[(size_t)((j + 1) * SEGLEN - 1) * DIM + d], C);
    w *= As[j];
    if (w < 1e-35f) break;   // uniform scalar: remaining terms underflow
  }

  float pa = 1.0f;
  for (int k = k0; k < k1; ++k) {
    pa *= ca[k];                                   // uniform scalar chain
    float H = fmaf(pa, C, st[(size_t)k * DIM + d]); // independent loads
    int t = bp[k];
    int tn = (k + 1 < n) ? bp[k + 1] : SEQL;
    for (int tt = t; tt < tn; ++tt) {
      ob[(size_t)tt * DIM + d] = H;
    }
  }
}

// ---------------------------------------------------------------------------
extern "C" void kernel_launch(void* const* d_in, const int* in_sizes, int n_in,
                              void* d_out, int out_size, void* d_ws, size_t ws_size,
                              hipStream_t stream) {
  const float* h    = (const float*)d_in[0];   // (2, 4096, 1024) f32
  const float* p    = (const float*)d_in[1];   // (2, 4096) f32
  const int*   mask = (const int*)d_in[2];     // (2, 4096) bool->int32
  float* out = (float*)d_out;                  // (2, 4096, 1024) f32

  // workspace layout (ws is 256 MB)
  int* bpos    = (int*)d_ws;                   // 2*4096 ints   (32 KB)
  int* nb      = bpos + 2 * SEQL;              // 16 ints
  float* coefA = (float*)(nb + 16);            // 2*4096 f32    (32 KB)
  float* coefB = coefA + 2 * SEQL;             // 2*4096 f32    (32 KB)
  float* Aseg  = coefB + 2 * SEQL;             // 2*NSEG f32    (2 KB)
  float* states = Aseg + 2 * NSEG;             // 2*4096*1024 f32 (32 MB worst)

  prep_kernel<<<dim3(2), 1024, 0, stream>>>(p, mask, bpos, nb, coefA, coefB, Aseg);

  dim3 sg(DIM / 256, NSEG, 2);
  scan_local_kernel<<<sg, 256, 0, stream>>>(h, bpos, coefA, coefB, nb, states);

  final_kernel<<<sg, 256, 0, stream>>>(bpos, coefA, nb, Aseg, states, out);
}